// Round 15
// baseline (503.919 us; speedup 1.0000x reference)
//
#include <hip/hip_runtime.h>
#include <stdint.h>

// MoE top-2-of-8, D=1024, FFN=4096, N=4096 tokens. fp16 MFMA, fp32 accum.
// R15: R14 base. GEMM epilogues LDS-packed: f16 results staged in a 32KB
// swizzled LDS tile, then copied out as 16B vector stores (8 stores/thread
// instead of 64 scattered 2B stores). partial adopts swizzled layout;
// k_combine un-swizzles on read. Workspace requirement: ~287 MiB.

#define NTOK 4096
#define DM   1024
#define DF   4096
#define NE   8
#define BM   128
#define MAX_RB 72
#define SLOT_CAP (MAX_RB * BM)

typedef _Float16 f16;
typedef __attribute__((ext_vector_type(8))) _Float16 f16x8;
typedef __attribute__((ext_vector_type(4))) _Float16 f16x4;
typedef __attribute__((ext_vector_type(4))) float    f32x4;

__device__ __forceinline__ void gl2lds16(const void* g, void* l) {
  __builtin_amdgcn_global_load_lds(
      (const __attribute__((address_space(1))) unsigned int*)g,
      (__attribute__((address_space(3))) unsigned int*)l, 16, 0, 0);
}

// ---------------- K1: fused convw (W1/W3 -> f16 swizzled tiles) + RMS/router --
__global__ __launch_bounds__(256) void k_conv_rms(
    const float* __restrict__ W1, const float* __restrict__ W3,
    f16* __restrict__ w16,
    const float* __restrict__ x, const float* __restrict__ rms_w,
    const float* __restrict__ rw, const float* __restrict__ rbias,
    f16* __restrict__ xn, int* __restrict__ topi, float* __restrict__ topw,
    int* __restrict__ counts)
{
  __shared__ f16 T[64][132];
  __shared__ float red[4][9];
  int tid = threadIdx.x;

  if (blockIdx.x < 2 * NE * 512) {
    // ---- weight conversion path ----
    int g = blockIdx.x;
    int tensor = g >> 12;
    int rem = g & 4095;
    int e = rem >> 9;
    int t = rem & 511;
    const float* W = (tensor == 0) ? W1 : W3;
    int np = t >> 4, kt = t & 15;
    const float* src = W + (size_t)e * DM * DF + (size_t)(kt * 64) * DF + np * 128;

    int q = tid & 31, kb = tid >> 5;
#pragma unroll
    for (int i = 0; i < 8; ++i) {
      int k = kb + 8 * i;
      f32x4 v = *(const f32x4*)(src + (size_t)k * DF + q * 4);
      f16x4 h4 = { (f16)v[0], (f16)v[1], (f16)v[2], (f16)v[3] };
      *(f16x4*)(&T[k][q * 4]) = h4;
    }
    __syncthreads();
    int n = tid >> 1;
    f16* dst = w16 + ((size_t)(tensor * NE + e) * 512 + t) * 8192 + n * 64 + (tid & 1) * 32;
#pragma unroll
    for (int qq = 0; qq < 4; ++qq) {
      int cs = (tid & 1) * 4 + qq;
      int cl = cs ^ (n & 7);
      f16x8 o;
#pragma unroll
      for (int j = 0; j < 8; ++j) o[j] = T[cl * 8 + j][n];
      *(f16x8*)(dst + qq * 8) = o;
    }
    return;
  }

  // ---- RMSNorm + router path ----
  int t = blockIdx.x - 2 * NE * 512;
  const float* xr = x + (size_t)t * DM;
  f32x4 xv = *(const f32x4*)(xr + tid * 4);
  f32x4 gw = *(const f32x4*)(rms_w + tid * 4);
  f32x4 gv = xv * gw;

  float v[9];
  v[8] = xv[0]*xv[0] + xv[1]*xv[1] + xv[2]*xv[2] + xv[3]*xv[3];
#pragma unroll
  for (int e = 0; e < NE; ++e) {
    f32x4 wv = *(const f32x4*)(rw + e * DM + tid * 4);
    v[e] = gv[0]*wv[0] + gv[1]*wv[1] + gv[2]*wv[2] + gv[3]*wv[3];
  }
#pragma unroll
  for (int off = 32; off; off >>= 1) {
#pragma unroll
    for (int j = 0; j < 9; ++j) v[j] += __shfl_xor(v[j], off);
  }
  int wave = tid >> 6, lane = tid & 63;
  if (lane == 0) {
#pragma unroll
    for (int j = 0; j < 9; ++j) red[wave][j] = v[j];
  }
  __syncthreads();
  float tot[9];
#pragma unroll
  for (int j = 0; j < 9; ++j)
    tot[j] = red[0][j] + red[1][j] + red[2][j] + red[3][j];

  float rinv = 1.0f / sqrtf(tot[8] * (1.0f / DM) + 1e-7f);
  float lg[NE];
#pragma unroll
  for (int e = 0; e < NE; ++e) lg[e] = tot[e] * rinv + rbias[e];

  int e1 = 0; float b1v = lg[0];
#pragma unroll
  for (int e = 1; e < NE; ++e) if (lg[e] > b1v) { b1v = lg[e]; e1 = e; }
  int e2 = -1; float b2v = -1e30f;
#pragma unroll
  for (int e = 0; e < NE; ++e) if (e != e1 && lg[e] > b2v) { b2v = lg[e]; e2 = e; }

  float r2 = expf(b2v - b1v);
  float w1 = 1.0f / (1.0f + r2);
  float w2 = r2 * w1;

  if (tid == 0) {
    topi[t * 2 + 0] = e1; topi[t * 2 + 1] = e2;
    topw[t * 2 + 0] = w1; topw[t * 2 + 1] = w2;
    atomicAdd(&counts[e1], 1);
    atomicAdd(&counts[e2], 1);
  }
  f16x4 o;
#pragma unroll
  for (int i = 0; i < 4; ++i) o[i] = (f16)(gv[i] * rinv);
  *(f16x4*)(xn + (size_t)t * DM + tid * 4) = o;
}

// ---------------- K2: padded offsets + row-block table + rb_start ------------
__global__ void k_build(const int* __restrict__ counts, int* __restrict__ po,
                        int2* __restrict__ rbtable, int* __restrict__ total_rb,
                        int* __restrict__ rb_start)
{
  if (threadIdx.x != 0 || blockIdx.x != 0) return;
  int off = 0, idx = 0;
  for (int e = 0; e < NE; ++e) {
    int c = counts[e];
    po[e] = off;
    rb_start[e] = idx;
    int nrb = (c + BM - 1) / BM;
    for (int r = 0; r < nrb; ++r) { rbtable[idx] = make_int2(e, off + r * BM); ++idx; }
    off += nrb * BM;
  }
  rb_start[NE] = idx;
  *total_rb = idx;
}

// ---------------- K3: slot assignment (+ inverse map) ----------------
__global__ __launch_bounds__(256) void k_assign(
    const int* __restrict__ topi, const float* __restrict__ topw,
    const int* __restrict__ po, int* __restrict__ cursors,
    int* __restrict__ slot_token, float* __restrict__ slot_w,
    int* __restrict__ tok2slot)
{
  int t = blockIdx.x * 256 + threadIdx.x;
  if (t >= NTOK) return;
#pragma unroll
  for (int k = 0; k < 2; ++k) {
    int e = topi[t * 2 + k];
    int pos = atomicAdd(&cursors[e], 1);
    int slot = po[e] + pos;
    slot_token[slot] = t;
    slot_w[slot] = topw[t * 2 + k];
    tok2slot[t * 2 + k] = slot;
  }
}

// ---------------- K4: grouped GEMM  h = silu(X*W1+b1)*(X*W3+b3) ----------------
// R6 structure; supertiled dispatch; LDS-packed epilogue (8x16B stores/thread).
__global__ __launch_bounds__(256, 3) void k_ffn13(
    const f16* __restrict__ xn, const int* __restrict__ slot_token,
    const int2* __restrict__ rbtable, const int* __restrict__ total_rb,
    const f16* __restrict__ w16,
    const float* __restrict__ b1, const float* __restrict__ b3,
    const float* __restrict__ W2, f16* __restrict__ w16_w2,
    f16* __restrict__ h)
{
  __shared__ __align__(16) char LB[49152];   // [A 16K][B1 16K][B3 16K]

  int bid = blockIdx.x;                    // 2304 = 8*288
  int xcd = bid & 7, i = bid >> 3;         // i 0..287
  int rbi = (i / 12) * 3 + (i % 3);        // 0..71 (A-supertiles of 3)
  int np  = xcd * 4 + ((i / 3) & 3);       // 0..31 (B-panels per XCD)
  int tid = threadIdx.x, lane = tid & 63, wave = tid >> 6;

  bool active = (rbi < *total_rb);
  if (active) {
    int2 ent = rbtable[rbi];
    int e = ent.x, row0 = ent.y;
    int n0 = np * 128;

    int wm = wave >> 1, wn = wave & 1;
    const f16* wb1 = w16 + ((size_t)(0 * NE + e) * 512 + np * 16) * 8192;
    const f16* wb3 = w16 + ((size_t)(1 * NE + e) * 512 + np * 16) * 8192;

    int tok[4];
#pragma unroll
    for (int q = 0; q < 4; ++q) {
      int m = q * 32 + wave * 8 + (lane >> 3);
      int tkn = slot_token[row0 + m];
      tok[q] = (tkn < 0) ? 0 : tkn;
    }
    int csx = (((lane & 7) ^ (lane >> 3)) << 3);
    int lin = wave * 512 + lane * 8;

    f32x4 acc1[4][4], acc3[4][4];
    f32x4 z = {0.f, 0.f, 0.f, 0.f};
#pragma unroll
    for (int i2 = 0; i2 < 4; ++i2)
#pragma unroll
      for (int j = 0; j < 4; ++j) { acc1[i2][j] = z; acc3[i2][j] = z; }

    for (int kt = 0; kt < DM / 64; ++kt) {
      int k0 = kt * 64;
      const f16* s1 = wb1 + (size_t)kt * 8192;
      const f16* s3 = wb3 + (size_t)kt * 8192;
#pragma unroll
      for (int q = 0; q < 4; ++q) {
        gl2lds16(xn + (size_t)tok[q] * DM + k0 + csx,
                 LB + q * 4096 + wave * 1024);
        gl2lds16(s1 + q * 2048 + lin, LB + 16384 + q * 4096 + wave * 1024);
        gl2lds16(s3 + q * 2048 + lin, LB + 32768 + q * 4096 + wave * 1024);
      }
      __syncthreads();
#pragma unroll
      for (int kh = 0; kh < 2; ++kh) {
        int kk = kh * 32 + (lane >> 4) * 8;
        f16x8 a[4];
#pragma unroll
        for (int fm = 0; fm < 4; ++fm) {
          int m = wm * 64 + fm * 16 + (lane & 15);
          a[fm] = *(const f16x8*)(LB + m * 128 + 2 * (kk ^ ((m & 7) << 3)));
        }
#pragma unroll
        for (int fn = 0; fn < 4; ++fn) {
          int n = wn * 64 + fn * 16 + (lane & 15);
          f16x8 bf1 = *(const f16x8*)(LB + 16384 + n * 128 + 2 * (kk ^ ((n & 7) << 3)));
          f16x8 bf3 = *(const f16x8*)(LB + 32768 + n * 128 + 2 * (kk ^ ((n & 7) << 3)));
#pragma unroll
          for (int fm = 0; fm < 4; ++fm) {
            acc1[fm][fn] = __builtin_amdgcn_mfma_f32_16x16x32_f16(a[fm], bf1, acc1[fm][fn], 0, 0, 0);
            acc3[fm][fn] = __builtin_amdgcn_mfma_f32_16x16x32_f16(a[fm], bf3, acc3[fm][fn], 0, 0, 0);
          }
        }
      }
      __syncthreads();
    }
    // epilogue: bias+silu+mul -> pack into 32KB swizzled LDS tile -> 16B stores
    f16* P = (f16*)LB;                       // [128 rows][128 f16], h-swizzled
#pragma unroll
    for (int fn = 0; fn < 4; ++fn) {
      int ncl = wn * 64 + fn * 16 + (lane & 15);          // 0..127
      int nc = n0 + ncl;
      float bb1 = b1[e * DF + nc], bb3 = b3[e * DF + nc];
#pragma unroll
      for (int fm = 0; fm < 4; ++fm) {
        int mbase = wm * 64 + fm * 16 + (lane >> 4) * 4;
#pragma unroll
        for (int r = 0; r < 4; ++r) {
          int sl = mbase + r;
          float u1 = acc1[fm][fn][r] + bb1;
          float u3 = acc3[fm][fn][r] + bb3;
          float hv = (u1 / (1.0f + __expf(-u1))) * u3;
          P[sl * 128 + (ncl & 64) + ((((ncl >> 3) & 7) ^ (sl & 7)) << 3) + (ncl & 7)] = (f16)hv;
        }
      }
    }
    __syncthreads();
    {
      int row = tid >> 1, half = tid & 1;
      const f16* src = P + row * 128 + half * 64;
      f16* dst = h + (size_t)(row0 + row) * DF + n0 + half * 64;
#pragma unroll
      for (int j = 0; j < 8; ++j)
        *(f16x8*)(dst + j * 8) = *(const f16x8*)(src + j * 8);
    }
  }

  // ---- fused W2 conversion: tiles 2*bid, 2*bid+1 (4096 total) ----
  f16 (*T)[132] = (f16(*)[132])(LB + 16384);   // 16.9 KiB
  int q = tid & 31, kb = tid >> 5;
  for (int j = 0; j < 2; ++j) {
    int tile = bid * 2 + j;
    if (tile >= NE * 512) break;
    int e2 = tile >> 9, t2 = tile & 511;
    int np2 = t2 >> 6, kt2 = t2 & 63;
    const float* src = W2 + (size_t)e2 * DM * DF + (size_t)(kt2 * 64) * DM + np2 * 128;
    __syncthreads();
#pragma unroll
    for (int i2 = 0; i2 < 8; ++i2) {
      int k = kb + 8 * i2;
      f32x4 v = *(const f32x4*)(src + (size_t)k * DM + q * 4);
      f16x4 h4 = { (f16)v[0], (f16)v[1], (f16)v[2], (f16)v[3] };
      *(f16x4*)(&T[k][q * 4]) = h4;
    }
    __syncthreads();
    int n = tid >> 1;
    f16* dst = w16_w2 + (size_t)(e2 * 512 + t2) * 8192 + n * 64 + (tid & 1) * 32;
#pragma unroll
    for (int qq = 0; qq < 4; ++qq) {
      int cs = (tid & 1) * 4 + qq;
      int cl = cs ^ (n & 7);
      f16x8 o8;
#pragma unroll
      for (int jj = 0; jj < 8; ++jj) o8[jj] = T[cl * 8 + jj][n];
      *(f16x8*)(dst + qq * 8) = o8;
    }
  }
}

// ---------------- K5: grouped GEMM partials  y[slot] = h*W2 (full K) --------
// Expert-per-XCD dispatch; LDS-packed epilogue; partial stored h-swizzled.
__global__ __launch_bounds__(256, 4) void k_ffn2(
    const f16* __restrict__ h,
    const int2* __restrict__ rbtable, const int* __restrict__ rb_start,
    const f16* __restrict__ w16_w2, f16* __restrict__ partial)
{
  __shared__ __align__(16) char LB[32768];   // [A 16K][B 16K]

  int bid = blockIdx.x;                 // 1536 = 8*192
  int xcd = bid & 7, i = bid >> 3;      // i 0..191
  int rbi_in  = i % 3;
  int np      = (i / 3) & 7;            // 0..7
  int rbi_out = i / 24;                 // 0..7
  int e = xcd;
  int base = rb_start[e];
  int nrb  = rb_start[e + 1] - base;
  int rbl = rbi_out * 3 + rbi_in;       // 0..23
  if (rbl >= nrb) return;
  int2 ent = rbtable[base + rbl];
  int row0 = ent.y;
  int n0 = np * 128;

  int tid = threadIdx.x, lane = tid & 63, wave = tid >> 6;
  int wm = wave >> 1, wn = wave & 1;
  const f16* wb = w16_w2 + ((size_t)e * 512 + np * 64) * 8192;
  int lin = wave * 512 + lane * 8;

  f32x4 acc[4][4];
  f32x4 z = {0.f, 0.f, 0.f, 0.f};
#pragma unroll
  for (int i2 = 0; i2 < 4; ++i2)
#pragma unroll
    for (int j = 0; j < 4; ++j) acc[i2][j] = z;

  for (int kt = 0; kt < 64; ++kt) {
    const f16* sB = wb + (size_t)kt * 8192;
    int k0 = kt * 64;
#pragma unroll
    for (int q = 0; q < 4; ++q) {
      int m = q * 32 + wave * 8 + (lane >> 3);
      gl2lds16(h + (size_t)(row0 + m) * DF + k0 + ((lane & 7) << 3),
               LB + q * 4096 + wave * 1024);
      gl2lds16(sB + q * 2048 + lin, LB + 16384 + q * 4096 + wave * 1024);
    }
    __syncthreads();
#pragma unroll
    for (int kh = 0; kh < 2; ++kh) {
      int kk = kh * 32 + (lane >> 4) * 8;
      f16x8 a[4];
#pragma unroll
      for (int fm = 0; fm < 4; ++fm) {
        int m = wm * 64 + fm * 16 + (lane & 15);
        a[fm] = *(const f16x8*)(LB + m * 128 + 2 * (kk ^ ((m & 7) << 3)));
      }
#pragma unroll
      for (int fn = 0; fn < 4; ++fn) {
        int n = wn * 64 + fn * 16 + (lane & 15);
        f16x8 bf = *(const f16x8*)(LB + 16384 + n * 128 + 2 * (kk ^ ((n & 7) << 3)));
#pragma unroll
        for (int fm = 0; fm < 4; ++fm)
          acc[fm][fn] = __builtin_amdgcn_mfma_f32_16x16x32_f16(a[fm], bf, acc[fm][fn], 0, 0, 0);
      }
    }
    __syncthreads();
  }
  // epilogue: pack into 32KB swizzled LDS tile -> 16B stores (no atomics)
  {
    f16* P = (f16*)LB;                       // [128 rows][128 f16], swizzled
#pragma unroll
    for (int fn = 0; fn < 4; ++fn) {
      int ncl = wn * 64 + fn * 16 + (lane & 15);
#pragma unroll
      for (int fm = 0; fm < 4; ++fm) {
        int mbase = wm * 64 + fm * 16 + (lane >> 4) * 4;
#pragma unroll
        for (int r = 0; r < 4; ++r) {
          int sl = mbase + r;
          P[sl * 128 + (ncl & 64) + ((((ncl >> 3) & 7) ^ (sl & 7)) << 3) + (ncl & 7)]
              = (f16)acc[fm][fn][r];
        }
      }
    }
    __syncthreads();
    int row = tid >> 1, half = tid & 1;
    const f16* src = P + row * 128 + half * 64;
    f16* dst = partial + ((size_t)(row0 + row) << 10) + n0 + half * 64;
#pragma unroll
    for (int j = 0; j < 8; ++j)
      *(f16x8*)(dst + j * 8) = *(const f16x8*)(src + j * 8);
  }
}

// ---------------- K6: combine  out[t] = sum_k c_k * (y_k + b2[e_k]) ----------
// partial is h-swizzled: un-swizzle in the read address (key = slot&7).
__global__ __launch_bounds__(256) void k_combine(
    const f16* __restrict__ partial, const int* __restrict__ tok2slot,
    const int* __restrict__ topi, const float* __restrict__ topw,
    const float* __restrict__ b2, float* __restrict__ out)
{
  int t = blockIdx.x;
  int nc = threadIdx.x * 4;
  int s1 = tok2slot[t * 2], s2 = tok2slot[t * 2 + 1];
  float c1 = topw[t * 2], c2 = topw[t * 2 + 1];
  int e1 = topi[t * 2], e2 = topi[t * 2 + 1];
  int off1 = (nc & ~63) + ((((nc >> 3) & 7) ^ (s1 & 7)) << 3) + (nc & 7);
  int off2 = (nc & ~63) + ((((nc >> 3) & 7) ^ (s2 & 7)) << 3) + (nc & 7);
  f16x4 p1 = *(const f16x4*)(partial + ((size_t)s1 << 10) + off1);
  f16x4 p2 = *(const f16x4*)(partial + ((size_t)s2 << 10) + off2);
  f32x4 bb1 = *(const f32x4*)(b2 + e1 * DM + nc);
  f32x4 bb2 = *(const f32x4*)(b2 + e2 * DM + nc);
  f32x4 o;
#pragma unroll
  for (int i = 0; i < 4; ++i)
    o[i] = c1 * ((float)p1[i] + bb1[i]) + c2 * ((float)p2[i] + bb2[i]);
  *(f32x4*)(out + ((size_t)t << 10) + nc) = o;
}

// ---------------- launch ----------------
extern "C" void kernel_launch(void* const* d_in, const int* in_sizes, int n_in,
                              void* d_out, int out_size, void* d_ws, size_t ws_size,
                              hipStream_t stream)
{
  const float* x     = (const float*)d_in[0];
  const float* rms_w = (const float*)d_in[2];
  const float* rw    = (const float*)d_in[3];
  const float* rbias = (const float*)d_in[4];
  const float* W1    = (const float*)d_in[5];
  const float* b1    = (const float*)d_in[6];
  const float* W2    = (const float*)d_in[7];
  const float* b2    = (const float*)d_in[8];
  const float* W3    = (const float*)d_in[9];
  const float* b3    = (const float*)d_in[10];
  float* out = (float*)d_out;

  char* ws = (char*)d_ws;
  size_t o = 0;
  f16* w16 = (f16*)(ws + o); o += (size_t)3 * NE * 512 * 8192 * 2;  // 201.3 MiB
  f16* h   = (f16*)(ws + o); o += (size_t)SLOT_CAP * DF * 2;        //  75.5 MiB
  f16* xn  = (f16*)(ws + o); o += (size_t)NTOK * DM * 2;            //   8   MiB
  int*   slot_token = (int*)(ws + o);   o += SLOT_CAP * 4;
  float* slot_w     = (float*)(ws + o); o += SLOT_CAP * 4;
  int*   topi       = (int*)(ws + o);   o += NTOK * 2 * 4;
  float* topw       = (float*)(ws + o); o += NTOK * 2 * 4;
  int*   tok2slot   = (int*)(ws + o);   o += NTOK * 2 * 4;
  int*   counts     = (int*)(ws + o);   o += 64;
  int*   cursors    = (int*)(ws + o);   o += 64;
  int*   po         = (int*)(ws + o);   o += 64;
  int*   total_rb   = (int*)(ws + o);   o += 64;
  int*   rb_start   = (int*)(ws + o);   o += 64;
  int2*  rbtable    = (int2*)(ws + o);  o += MAX_RB * 8;
  (void)ws_size; (void)in_sizes; (void)n_in;

  // w16 layout: [W1][W3][W2], 67.1 MiB each.
  f16* w16_w2 = w16 + (size_t)2 * NE * 512 * 8192;
  // partial[SLOT_CAP][1024] f16 (18.9 MiB) overlays dead W1 region.
  f16* partial = w16;

  // k_combine fully writes out[0 .. NTOK*DM); only zero the aux tail.
  size_t covered = (size_t)NTOK * DM;
  if ((size_t)out_size > covered)
    hipMemsetAsync((char*)d_out + covered * 4, 0, ((size_t)out_size - covered) * 4, stream);
  hipMemsetAsync(counts, 0, 128, stream);                   // counts + cursors
  hipMemsetAsync(slot_token, 0xFF, SLOT_CAP * 4, stream);   // pad slots -> -1

  k_conv_rms<<<2 * NE * 512 + NTOK, 256, 0, stream>>>(
      W1, W3, w16, x, rms_w, rw, rbias, xn, topi, topw, counts);
  k_build<<<1, 64, 0, stream>>>(counts, po, rbtable, total_rb, rb_start);
  k_assign<<<16, 256, 0, stream>>>(topi, topw, po, cursors, slot_token, slot_w, tok2slot);
  k_ffn13<<<8 * 288, 256, 0, stream>>>(xn, slot_token, rbtable, total_rb,
                                       w16, b1, b3, W2, w16_w2, h);
  k_ffn2<<<8 * 192, 256, 0, stream>>>(h, rbtable, rb_start, w16_w2, partial);
  k_combine<<<NTOK, 256, 0, stream>>>(partial, tok2slot, topi, topw, b2, out);
}

// Round 16
// 492.507 us; speedup vs baseline: 1.0232x; 1.0232x over previous
//
#include <hip/hip_runtime.h>
#include <stdint.h>

// MoE top-2-of-8, D=1024, FFN=4096, N=4096 tokens. fp16 MFMA, fp32 accum.
// R16 = R14 champion, reverted verbatim (R15's LDS-pack epilogue regressed:
// +2e6 bank conflicts; scattered 2B global stores are cheaper than LDS repack).
// ffn2: expert-per-XCD dispatch, kc=1, partial+combine (no atomics).
// Workspace requirement: ~287 MiB.

#define NTOK 4096
#define DM   1024
#define DF   4096
#define NE   8
#define BM   128
#define MAX_RB 72
#define SLOT_CAP (MAX_RB * BM)

typedef _Float16 f16;
typedef __attribute__((ext_vector_type(8))) _Float16 f16x8;
typedef __attribute__((ext_vector_type(4))) _Float16 f16x4;
typedef __attribute__((ext_vector_type(4))) float    f32x4;

__device__ __forceinline__ void gl2lds16(const void* g, void* l) {
  __builtin_amdgcn_global_load_lds(
      (const __attribute__((address_space(1))) unsigned int*)g,
      (__attribute__((address_space(3))) unsigned int*)l, 16, 0, 0);
}

// ---------------- K1: fused convw (W1/W3 -> f16 swizzled tiles) + RMS/router --
__global__ __launch_bounds__(256) void k_conv_rms(
    const float* __restrict__ W1, const float* __restrict__ W3,
    f16* __restrict__ w16,
    const float* __restrict__ x, const float* __restrict__ rms_w,
    const float* __restrict__ rw, const float* __restrict__ rbias,
    f16* __restrict__ xn, int* __restrict__ topi, float* __restrict__ topw,
    int* __restrict__ counts)
{
  __shared__ f16 T[64][132];
  __shared__ float red[4][9];
  int tid = threadIdx.x;

  if (blockIdx.x < 2 * NE * 512) {
    // ---- weight conversion path ----
    int g = blockIdx.x;
    int tensor = g >> 12;
    int rem = g & 4095;
    int e = rem >> 9;
    int t = rem & 511;
    const float* W = (tensor == 0) ? W1 : W3;
    int np = t >> 4, kt = t & 15;
    const float* src = W + (size_t)e * DM * DF + (size_t)(kt * 64) * DF + np * 128;

    int q = tid & 31, kb = tid >> 5;
#pragma unroll
    for (int i = 0; i < 8; ++i) {
      int k = kb + 8 * i;
      f32x4 v = *(const f32x4*)(src + (size_t)k * DF + q * 4);
      f16x4 h4 = { (f16)v[0], (f16)v[1], (f16)v[2], (f16)v[3] };
      *(f16x4*)(&T[k][q * 4]) = h4;
    }
    __syncthreads();
    int n = tid >> 1;
    f16* dst = w16 + ((size_t)(tensor * NE + e) * 512 + t) * 8192 + n * 64 + (tid & 1) * 32;
#pragma unroll
    for (int qq = 0; qq < 4; ++qq) {
      int cs = (tid & 1) * 4 + qq;
      int cl = cs ^ (n & 7);
      f16x8 o;
#pragma unroll
      for (int j = 0; j < 8; ++j) o[j] = T[cl * 8 + j][n];
      *(f16x8*)(dst + qq * 8) = o;
    }
    return;
  }

  // ---- RMSNorm + router path ----
  int t = blockIdx.x - 2 * NE * 512;
  const float* xr = x + (size_t)t * DM;
  f32x4 xv = *(const f32x4*)(xr + tid * 4);
  f32x4 gw = *(const f32x4*)(rms_w + tid * 4);
  f32x4 gv = xv * gw;

  float v[9];
  v[8] = xv[0]*xv[0] + xv[1]*xv[1] + xv[2]*xv[2] + xv[3]*xv[3];
#pragma unroll
  for (int e = 0; e < NE; ++e) {
    f32x4 wv = *(const f32x4*)(rw + e * DM + tid * 4);
    v[e] = gv[0]*wv[0] + gv[1]*wv[1] + gv[2]*wv[2] + gv[3]*wv[3];
  }
#pragma unroll
  for (int off = 32; off; off >>= 1) {
#pragma unroll
    for (int j = 0; j < 9; ++j) v[j] += __shfl_xor(v[j], off);
  }
  int wave = tid >> 6, lane = tid & 63;
  if (lane == 0) {
#pragma unroll
    for (int j = 0; j < 9; ++j) red[wave][j] = v[j];
  }
  __syncthreads();
  float tot[9];
#pragma unroll
  for (int j = 0; j < 9; ++j)
    tot[j] = red[0][j] + red[1][j] + red[2][j] + red[3][j];

  float rinv = 1.0f / sqrtf(tot[8] * (1.0f / DM) + 1e-7f);
  float lg[NE];
#pragma unroll
  for (int e = 0; e < NE; ++e) lg[e] = tot[e] * rinv + rbias[e];

  int e1 = 0; float b1v = lg[0];
#pragma unroll
  for (int e = 1; e < NE; ++e) if (lg[e] > b1v) { b1v = lg[e]; e1 = e; }
  int e2 = -1; float b2v = -1e30f;
#pragma unroll
  for (int e = 0; e < NE; ++e) if (e != e1 && lg[e] > b2v) { b2v = lg[e]; e2 = e; }

  float r2 = expf(b2v - b1v);
  float w1 = 1.0f / (1.0f + r2);
  float w2 = r2 * w1;

  if (tid == 0) {
    topi[t * 2 + 0] = e1; topi[t * 2 + 1] = e2;
    topw[t * 2 + 0] = w1; topw[t * 2 + 1] = w2;
    atomicAdd(&counts[e1], 1);
    atomicAdd(&counts[e2], 1);
  }
  f16x4 o;
#pragma unroll
  for (int i = 0; i < 4; ++i) o[i] = (f16)(gv[i] * rinv);
  *(f16x4*)(xn + (size_t)t * DM + tid * 4) = o;
}

// ---------------- K2: padded offsets + row-block table + rb_start ------------
__global__ void k_build(const int* __restrict__ counts, int* __restrict__ po,
                        int2* __restrict__ rbtable, int* __restrict__ total_rb,
                        int* __restrict__ rb_start)
{
  if (threadIdx.x != 0 || blockIdx.x != 0) return;
  int off = 0, idx = 0;
  for (int e = 0; e < NE; ++e) {
    int c = counts[e];
    po[e] = off;
    rb_start[e] = idx;
    int nrb = (c + BM - 1) / BM;
    for (int r = 0; r < nrb; ++r) { rbtable[idx] = make_int2(e, off + r * BM); ++idx; }
    off += nrb * BM;
  }
  rb_start[NE] = idx;
  *total_rb = idx;
}

// ---------------- K3: slot assignment (+ inverse map) ----------------
__global__ __launch_bounds__(256) void k_assign(
    const int* __restrict__ topi, const float* __restrict__ topw,
    const int* __restrict__ po, int* __restrict__ cursors,
    int* __restrict__ slot_token, float* __restrict__ slot_w,
    int* __restrict__ tok2slot)
{
  int t = blockIdx.x * 256 + threadIdx.x;
  if (t >= NTOK) return;
#pragma unroll
  for (int k = 0; k < 2; ++k) {
    int e = topi[t * 2 + k];
    int pos = atomicAdd(&cursors[e], 1);
    int slot = po[e] + pos;
    slot_token[slot] = t;
    slot_w[slot] = topw[t * 2 + k];
    tok2slot[t * 2 + k] = slot;
  }
}

// ---------------- K4: grouped GEMM  h = silu(X*W1+b1)*(X*W3+b3) ----------------
// R6 structure; supertiled dispatch: 3-rbi A-groups x 4 np per XCD.
__global__ __launch_bounds__(256, 3) void k_ffn13(
    const f16* __restrict__ xn, const int* __restrict__ slot_token,
    const int2* __restrict__ rbtable, const int* __restrict__ total_rb,
    const f16* __restrict__ w16,
    const float* __restrict__ b1, const float* __restrict__ b3,
    const float* __restrict__ W2, f16* __restrict__ w16_w2,
    f16* __restrict__ h)
{
  __shared__ __align__(16) f16 As[128 * 64];
  __shared__ __align__(16) f16 Bs[2][128 * 64];

  int bid = blockIdx.x;                    // 2304 = 8*288
  int xcd = bid & 7, i = bid >> 3;         // i 0..287
  int rbi = (i / 12) * 3 + (i % 3);        // 0..71 (A-supertiles of 3)
  int np  = xcd * 4 + ((i / 3) & 3);       // 0..31 (B-panels per XCD)
  int tid = threadIdx.x, lane = tid & 63, wave = tid >> 6;

  bool active = (rbi < *total_rb);
  if (active) {
    int2 ent = rbtable[rbi];
    int e = ent.x, row0 = ent.y;
    int n0 = np * 128;

    int wm = wave >> 1, wn = wave & 1;
    const f16* wb1 = w16 + ((size_t)(0 * NE + e) * 512 + np * 16) * 8192;
    const f16* wb3 = w16 + ((size_t)(1 * NE + e) * 512 + np * 16) * 8192;

    int tok[4];
#pragma unroll
    for (int q = 0; q < 4; ++q) {
      int m = q * 32 + wave * 8 + (lane >> 3);
      int tkn = slot_token[row0 + m];
      tok[q] = (tkn < 0) ? 0 : tkn;
    }
    int csx = (((lane & 7) ^ (lane >> 3)) << 3);
    int lin = wave * 512 + lane * 8;

    f32x4 acc1[4][4], acc3[4][4];
    f32x4 z = {0.f, 0.f, 0.f, 0.f};
#pragma unroll
    for (int i2 = 0; i2 < 4; ++i2)
#pragma unroll
      for (int j = 0; j < 4; ++j) { acc1[i2][j] = z; acc3[i2][j] = z; }

    for (int kt = 0; kt < DM / 64; ++kt) {
      int k0 = kt * 64;
      const f16* s1 = wb1 + (size_t)kt * 8192;
      const f16* s3 = wb3 + (size_t)kt * 8192;
#pragma unroll
      for (int q = 0; q < 4; ++q) {
        gl2lds16(xn + (size_t)tok[q] * DM + k0 + csx,
                 (char*)As + q * 4096 + wave * 1024);
        gl2lds16(s1 + q * 2048 + lin, (char*)Bs[0] + q * 4096 + wave * 1024);
        gl2lds16(s3 + q * 2048 + lin, (char*)Bs[1] + q * 4096 + wave * 1024);
      }
      __syncthreads();
#pragma unroll
      for (int kh = 0; kh < 2; ++kh) {
        int kk = kh * 32 + (lane >> 4) * 8;
        f16x8 a[4];
#pragma unroll
        for (int fm = 0; fm < 4; ++fm) {
          int m = wm * 64 + fm * 16 + (lane & 15);
          a[fm] = *(const f16x8*)((char*)As + m * 128 + 2 * (kk ^ ((m & 7) << 3)));
        }
#pragma unroll
        for (int fn = 0; fn < 4; ++fn) {
          int n = wn * 64 + fn * 16 + (lane & 15);
          f16x8 bf1 = *(const f16x8*)((char*)Bs[0] + n * 128 + 2 * (kk ^ ((n & 7) << 3)));
          f16x8 bf3 = *(const f16x8*)((char*)Bs[1] + n * 128 + 2 * (kk ^ ((n & 7) << 3)));
#pragma unroll
          for (int fm = 0; fm < 4; ++fm) {
            acc1[fm][fn] = __builtin_amdgcn_mfma_f32_16x16x32_f16(a[fm], bf1, acc1[fm][fn], 0, 0, 0);
            acc3[fm][fn] = __builtin_amdgcn_mfma_f32_16x16x32_f16(a[fm], bf3, acc3[fm][fn], 0, 0, 0);
          }
        }
      }
      __syncthreads();
    }
    // epilogue: bias + silu + mul; write h pre-swizzled for ffn2's linear A-stage
#pragma unroll
    for (int fn = 0; fn < 4; ++fn) {
      int nc = n0 + wn * 64 + fn * 16 + (lane & 15);
      float bb1 = b1[e * DF + nc], bb3 = b3[e * DF + nc];
#pragma unroll
      for (int fm = 0; fm < 4; ++fm) {
        int mbase = wm * 64 + fm * 16 + (lane >> 4) * 4;
#pragma unroll
        for (int r = 0; r < 4; ++r) {
          int sl = mbase + r;
          float u1 = acc1[fm][fn][r] + bb1;
          float u3 = acc3[fm][fn][r] + bb3;
          float hv = (u1 / (1.0f + __expf(-u1))) * u3;
          size_t off = (size_t)(row0 + sl) * DF + (nc & ~63)
                     + ((((nc >> 3) & 7) ^ (sl & 7)) << 3) + (nc & 7);
          h[off] = (f16)hv;
        }
      }
    }
  }

  // ---- fused W2 conversion: tiles 2*bid, 2*bid+1 (4096 total) ----
  f16 (*T)[132] = (f16(*)[132])(&Bs[0][0]);   // 16.9 KiB, fits in Bs
  int q = tid & 31, kb = tid >> 5;
  for (int j = 0; j < 2; ++j) {
    int tile = bid * 2 + j;
    if (tile >= NE * 512) break;
    int e2 = tile >> 9, t2 = tile & 511;
    int np2 = t2 >> 6, kt2 = t2 & 63;
    const float* src = W2 + (size_t)e2 * DM * DF + (size_t)(kt2 * 64) * DM + np2 * 128;
    __syncthreads();
#pragma unroll
    for (int i2 = 0; i2 < 8; ++i2) {
      int k = kb + 8 * i2;
      f32x4 v = *(const f32x4*)(src + (size_t)k * DM + q * 4);
      f16x4 h4 = { (f16)v[0], (f16)v[1], (f16)v[2], (f16)v[3] };
      *(f16x4*)(&T[k][q * 4]) = h4;
    }
    __syncthreads();
    int n = tid >> 1;
    f16* dst = w16_w2 + (size_t)(e2 * 512 + t2) * 8192 + n * 64 + (tid & 1) * 32;
#pragma unroll
    for (int qq = 0; qq < 4; ++qq) {
      int cs = (tid & 1) * 4 + qq;
      int cl = cs ^ (n & 7);
      f16x8 o8;
#pragma unroll
      for (int jj = 0; jj < 8; ++jj) o8[jj] = T[cl * 8 + jj][n];
      *(f16x8*)(dst + qq * 8) = o8;
    }
  }
}

// ---------------- K5: grouped GEMM partials  y[slot] = h*W2 (full K) --------
// Expert-per-XCD dispatch: e = xcd; per XCD i 0..191: (rbi_in 3 | np 8 |
// rbi_out 8) -> rbi_local 0..23. 3 consecutive blocks share the SAME (e,np)
// W2 panel; 3-rbi h stripe (3MB) + panel (1MB) fit L2 across the np sweep.
__global__ __launch_bounds__(256, 4) void k_ffn2(
    const f16* __restrict__ h,
    const int2* __restrict__ rbtable, const int* __restrict__ rb_start,
    const f16* __restrict__ w16_w2, f16* __restrict__ partial)
{
  __shared__ __align__(16) f16 As[128 * 64];
  __shared__ __align__(16) f16 Bsh[128 * 64];

  int bid = blockIdx.x;                 // 1536 = 8*192
  int xcd = bid & 7, i = bid >> 3;      // i 0..191
  int rbi_in  = i % 3;
  int np      = (i / 3) & 7;            // 0..7
  int rbi_out = i / 24;                 // 0..7
  int e = xcd;
  int base = rb_start[e];
  int nrb  = rb_start[e + 1] - base;
  int rbl = rbi_out * 3 + rbi_in;       // 0..23
  if (rbl >= nrb) return;
  int2 ent = rbtable[base + rbl];
  int row0 = ent.y;
  int n0 = np * 128;

  int tid = threadIdx.x, lane = tid & 63, wave = tid >> 6;
  int wm = wave >> 1, wn = wave & 1;
  const f16* wb = w16_w2 + ((size_t)e * 512 + np * 64) * 8192;
  int lin = wave * 512 + lane * 8;

  f32x4 acc[4][4];
  f32x4 z = {0.f, 0.f, 0.f, 0.f};
#pragma unroll
  for (int i2 = 0; i2 < 4; ++i2)
#pragma unroll
    for (int j = 0; j < 4; ++j) acc[i2][j] = z;

  for (int kt = 0; kt < 64; ++kt) {
    const f16* sB = wb + (size_t)kt * 8192;
    int k0 = kt * 64;
#pragma unroll
    for (int q = 0; q < 4; ++q) {
      int m = q * 32 + wave * 8 + (lane >> 3);
      gl2lds16(h + (size_t)(row0 + m) * DF + k0 + ((lane & 7) << 3),
               (char*)As + q * 4096 + wave * 1024);
      gl2lds16(sB + q * 2048 + lin, (char*)Bsh + q * 4096 + wave * 1024);
    }
    __syncthreads();
#pragma unroll
    for (int kh = 0; kh < 2; ++kh) {
      int kk = kh * 32 + (lane >> 4) * 8;
      f16x8 a[4];
#pragma unroll
      for (int fm = 0; fm < 4; ++fm) {
        int m = wm * 64 + fm * 16 + (lane & 15);
        a[fm] = *(const f16x8*)((char*)As + m * 128 + 2 * (kk ^ ((m & 7) << 3)));
      }
#pragma unroll
      for (int fn = 0; fn < 4; ++fn) {
        int n = wn * 64 + fn * 16 + (lane & 15);
        f16x8 bf = *(const f16x8*)((char*)Bsh + n * 128 + 2 * (kk ^ ((n & 7) << 3)));
#pragma unroll
        for (int fm = 0; fm < 4; ++fm)
          acc[fm][fn] = __builtin_amdgcn_mfma_f32_16x16x32_f16(a[fm], bf, acc[fm][fn], 0, 0, 0);
      }
    }
    __syncthreads();
  }
  // epilogue: plain fp16 partial stores (non-overlapping, no atomics)
#pragma unroll
  for (int fn = 0; fn < 4; ++fn) {
    int nc = n0 + wn * 64 + fn * 16 + (lane & 15);
#pragma unroll
    for (int fm = 0; fm < 4; ++fm) {
      int mbase = wm * 64 + fm * 16 + (lane >> 4) * 4;
#pragma unroll
      for (int r = 0; r < 4; ++r) {
        int slot = row0 + mbase + r;
        partial[((size_t)slot << 10) + nc] = (f16)acc[fm][fn][r];
      }
    }
  }
}

// ---------------- K6: combine  out[t] = sum_k c_k * (y_k + b2[e_k]) ----------
__global__ __launch_bounds__(256) void k_combine(
    const f16* __restrict__ partial, const int* __restrict__ tok2slot,
    const int* __restrict__ topi, const float* __restrict__ topw,
    const float* __restrict__ b2, float* __restrict__ out)
{
  int t = blockIdx.x;
  int nc = threadIdx.x * 4;
  int s1 = tok2slot[t * 2], s2 = tok2slot[t * 2 + 1];
  float c1 = topw[t * 2], c2 = topw[t * 2 + 1];
  int e1 = topi[t * 2], e2 = topi[t * 2 + 1];
  f16x4 p1 = *(const f16x4*)(partial + ((size_t)s1 << 10) + nc);
  f16x4 p2 = *(const f16x4*)(partial + ((size_t)s2 << 10) + nc);
  f32x4 bb1 = *(const f32x4*)(b2 + e1 * DM + nc);
  f32x4 bb2 = *(const f32x4*)(b2 + e2 * DM + nc);
  f32x4 o;
#pragma unroll
  for (int i = 0; i < 4; ++i)
    o[i] = c1 * ((float)p1[i] + bb1[i]) + c2 * ((float)p2[i] + bb2[i]);
  *(f32x4*)(out + ((size_t)t << 10) + nc) = o;
}

// ---------------- launch ----------------
extern "C" void kernel_launch(void* const* d_in, const int* in_sizes, int n_in,
                              void* d_out, int out_size, void* d_ws, size_t ws_size,
                              hipStream_t stream)
{
  const float* x     = (const float*)d_in[0];
  const float* rms_w = (const float*)d_in[2];
  const float* rw    = (const float*)d_in[3];
  const float* rbias = (const float*)d_in[4];
  const float* W1    = (const float*)d_in[5];
  const float* b1    = (const float*)d_in[6];
  const float* W2    = (const float*)d_in[7];
  const float* b2    = (const float*)d_in[8];
  const float* W3    = (const float*)d_in[9];
  const float* b3    = (const float*)d_in[10];
  float* out = (float*)d_out;

  char* ws = (char*)d_ws;
  size_t o = 0;
  f16* w16 = (f16*)(ws + o); o += (size_t)3 * NE * 512 * 8192 * 2;  // 201.3 MiB
  f16* h   = (f16*)(ws + o); o += (size_t)SLOT_CAP * DF * 2;        //  75.5 MiB
  f16* xn  = (f16*)(ws + o); o += (size_t)NTOK * DM * 2;            //   8   MiB
  int*   slot_token = (int*)(ws + o);   o += SLOT_CAP * 4;
  float* slot_w     = (float*)(ws + o); o += SLOT_CAP * 4;
  int*   topi       = (int*)(ws + o);   o += NTOK * 2 * 4;
  float* topw       = (float*)(ws + o); o += NTOK * 2 * 4;
  int*   tok2slot   = (int*)(ws + o);   o += NTOK * 2 * 4;
  int*   counts     = (int*)(ws + o);   o += 64;
  int*   cursors    = (int*)(ws + o);   o += 64;
  int*   po         = (int*)(ws + o);   o += 64;
  int*   total_rb   = (int*)(ws + o);   o += 64;
  int*   rb_start   = (int*)(ws + o);   o += 64;
  int2*  rbtable    = (int2*)(ws + o);  o += MAX_RB * 8;
  (void)ws_size; (void)in_sizes; (void)n_in;

  // w16 layout: [W1][W3][W2], 67.1 MiB each.
  f16* w16_w2 = w16 + (size_t)2 * NE * 512 * 8192;
  // partial[SLOT_CAP][1024] f16 (18.9 MiB) overlays dead W1 region.
  f16* partial = w16;

  // k_combine fully writes out[0 .. NTOK*DM); only zero the aux tail.
  size_t covered = (size_t)NTOK * DM;
  if ((size_t)out_size > covered)
    hipMemsetAsync((char*)d_out + covered * 4, 0, ((size_t)out_size - covered) * 4, stream);
  hipMemsetAsync(counts, 0, 128, stream);                   // counts + cursors
  hipMemsetAsync(slot_token, 0xFF, SLOT_CAP * 4, stream);   // pad slots -> -1

  k_conv_rms<<<2 * NE * 512 + NTOK, 256, 0, stream>>>(
      W1, W3, w16, x, rms_w, rw, rbias, xn, topi, topw, counts);
  k_build<<<1, 64, 0, stream>>>(counts, po, rbtable, total_rb, rb_start);
  k_assign<<<16, 256, 0, stream>>>(topi, topw, po, cursors, slot_token, slot_w, tok2slot);
  k_ffn13<<<8 * 288, 256, 0, stream>>>(xn, slot_token, rbtable, total_rb,
                                       w16, b1, b3, W2, w16_w2, h);
  k_ffn2<<<8 * 192, 256, 0, stream>>>(h, rbtable, rb_start, w16_w2, partial);
  k_combine<<<NTOK, 256, 0, stream>>>(partial, tok2slot, topi, topw, b2, out);
}